// Round 2
// baseline (232.085 us; speedup 1.0000x reference)
//
#include <hip/hip_runtime.h>
#include <hip/hip_fp16.h>

#define DIM 64
#define BIN_SHIFT 7
#define BINSZ 128      // nodes per bin
#define MAXBINS 1024   // supports N up to 131072
#define PB 512         // edge-slice blocks for hist/bucket (power of 2)
#define PB_LOG 9

typedef __attribute__((ext_vector_type(2))) float floatx2;

// ---------------- pass 1: per-block LDS histogram -> C[blk][bin] ----------------

__global__ __launch_bounds__(256) void k_hist(const int* __restrict__ dst,
                                              int* __restrict__ C, int E, int NB) {
    __shared__ int h[MAXBINS];
    for (int i = threadIdx.x; i < NB; i += 256) h[i] = 0;
    __syncthreads();
    int per = (E + PB - 1) / PB;
    int e0 = blockIdx.x * per;
    int e1 = e0 + per; if (e1 > E) e1 = E;
    for (int e = e0 + (int)threadIdx.x; e < e1; e += 256)
        atomicAdd(&h[dst[e] >> BIN_SHIFT], 1);
    __syncthreads();
    for (int i = threadIdx.x; i < NB; i += 256)
        C[blockIdx.x * NB + i] = h[i];
}

// ---------------- pass 2a: chunk-local exclusive scan of C (bin-major order) ----------------

__global__ __launch_bounds__(1024) void k_scanA(const int* __restrict__ C,
                                                int* __restrict__ S,
                                                int* __restrict__ bsums, int NB, int M) {
    __shared__ int sh[1024];
    int tid = threadIdx.x;
    int j0 = blockIdx.x * 4096 + tid * 4;
    int v[4]; int sum = 0;
#pragma unroll
    for (int t = 0; t < 4; ++t) {
        int j = j0 + t; int x = 0;
        if (j < M) { int bin = j >> PB_LOG, blk = j & (PB - 1); x = C[blk * NB + bin]; }
        v[t] = sum; sum += x;
    }
    sh[tid] = sum;
    __syncthreads();
#pragma unroll
    for (int d = 1; d < 1024; d <<= 1) {
        int t = (tid >= d) ? sh[tid - d] : 0;
        __syncthreads();
        sh[tid] += t;
        __syncthreads();
    }
    int excl = sh[tid] - sum;
#pragma unroll
    for (int t = 0; t < 4; ++t) {
        int j = j0 + t;
        if (j < M) S[j] = excl + v[t];
    }
    if (tid == 1023) bsums[blockIdx.x] = sh[1023];
}

// ---------------- pass 2b: exclusive scan of chunk sums ----------------

__global__ __launch_bounds__(1024) void k_scanB(int* __restrict__ bsums, int nb) {
    __shared__ int s[1024];
    int tid = threadIdx.x;
    int v = (tid < nb) ? bsums[tid] : 0;
    s[tid] = v;
    __syncthreads();
#pragma unroll
    for (int d = 1; d < 1024; d <<= 1) {
        int t = (tid >= d) ? s[tid - d] : 0;
        __syncthreads();
        s[tid] += t;
        __syncthreads();
    }
    if (tid < nb) bsums[tid] = s[tid] - v;
}

// ---------------- pass 3: one-pass bucket scatter, LDS cursors ----------------

__global__ __launch_bounds__(256) void k_bucket(const int* __restrict__ src,
                                                const int* __restrict__ dst,
                                                const int* __restrict__ S,
                                                const int* __restrict__ bsums,
                                                int* __restrict__ bkt, int E, int NB) {
    __shared__ int lcur[MAXBINS];
    int blk = blockIdx.x;
    for (int i = threadIdx.x; i < NB; i += 256) {
        int j = i * PB + blk;
        lcur[i] = S[j] + bsums[j >> 12];
    }
    __syncthreads();
    int per = (E + PB - 1) / PB;
    int e0 = blk * per;
    int e1 = e0 + per; if (e1 > E) e1 = E;
    for (int e = e0 + (int)threadIdx.x; e < e1; e += 256) {
        int d = dst[e];
        int pos = atomicAdd(&lcur[d >> BIN_SHIFT], 1);
        bkt[pos] = src[e] | ((d & (BINSZ - 1)) << 24);
    }
}

// ---------------- pass 4: per-bin counting sort -> csr, off, dinv, nperm; + gbound ----------------
// nperm: nodes of each 128-bin reordered by ascending degree, so gather waves (4 nodes
// of 16 consecutive nperm slots) carry near-equal degrees -> no exec-mask divergence.

__global__ __launch_bounds__(256) void k_binsort(const int* __restrict__ bkt,
                                                 const int* __restrict__ S,
                                                 const int* __restrict__ bsums,
                                                 int* __restrict__ csr,
                                                 int* __restrict__ off,
                                                 float* __restrict__ dinv,
                                                 const int* __restrict__ batch,
                                                 int* __restrict__ goff,
                                                 int* __restrict__ nperm,
                                                 int N, int G, int E, int NB) {
    __shared__ int cnt[BINSZ], bas[BINSZ], cur[BINSZ];
    __shared__ int wsum[4];
    int tid = threadIdx.x;
    int b = blockIdx.x;
    int j0 = b << PB_LOG;
    int s0 = S[j0] + bsums[j0 >> 12];
    int s1 = E;
    if (b + 1 < NB) { int j1 = (b + 1) << PB_LOG; s1 = S[j1] + bsums[j1 >> 12]; }
    if (tid < BINSZ) { cnt[tid] = 0; cur[tid] = 0; }
    __syncthreads();
    for (int i = s0 + tid; i < s1; i += 256)
        atomicAdd(&cnt[(bkt[i] >> 24) & (BINSZ - 1)], 1);
    __syncthreads();
    int my = (tid < BINSZ) ? cnt[tid] : 0;
    int lane = tid & 63, wv = tid >> 6;
    int x = my;
#pragma unroll
    for (int d = 1; d < 64; d <<= 1) {
        int t = __shfl_up(x, d);
        if (lane >= d) x += t;
    }
    if (lane == 63) wsum[wv] = x;
    __syncthreads();
    int prefix = 0;
    for (int w = 0; w < wv; ++w) prefix += wsum[w];
    int ex = x + prefix - my;               // exclusive base
    if (tid < BINSZ) {
        bas[tid] = ex;
        int v = (b << BIN_SHIFT) + tid;
        if (v < N) {
            off[v] = s0 + ex;
            dinv[v] = rsqrtf((float)(my + 1));   // +1 self-loop
            if (v == N - 1) off[N] = E;
            // fused gbound (batch sorted)
            int bb = batch[v];
            int prev = (v == 0) ? -1 : batch[v - 1];
            for (int g = prev + 1; g <= bb; ++g) goff[g] = v;
            if (v == N - 1)
                for (int g = bb + 1; g <= G; ++g) goff[g] = N;
        }
    }
    // degree-rank permutation within this bin (cnt[] still holds degrees)
    if (tid < BINSZ) {
        int v = (b << BIN_SHIFT) + tid;
        if (v < N) {
            int nvalid = N - (b << BIN_SHIFT);
            if (nvalid > BINSZ) nvalid = BINSZ;
            int d = my, rk = 0;
            for (int j = 0; j < nvalid; ++j) {
                int dj = cnt[j];
                rk += (int)((dj < d) || (dj == d && j < tid));
            }
            nperm[(b << BIN_SHIFT) + rk] = v;
        } else {
            nperm[v] = N;                    // padding sentinel
        }
    }
    __syncthreads();
    for (int i = s0 + tid; i < s1; i += 256) {
        int p = bkt[i];
        int lo = (p >> 24) & (BINSZ - 1);
        int li = atomicAdd(&cur[lo], 1);
        csr[s0 + bas[lo] + li] = p & 0xFFFFFF;
    }
}

// ---------------- skinny GEMM (16-row blocks): hs[row] = (X[row] @ W) * dinv[row] ----------------
// fp8 e4m3 output (one uint per 4 cols). Row N = zeros (gather padding).

__global__ __launch_bounds__(256) void k_gemm(const float* __restrict__ Xf,
                                              const float* __restrict__ W,
                                              const float* __restrict__ dinv,
                                              unsigned int* __restrict__ Y8, int N) {
    __shared__ float Ws[64 * 64];
    __shared__ float Xs[16 * 64];
    int tid = threadIdx.x;
#pragma unroll
    for (int i = 0; i < 16; ++i) Ws[tid + 256 * i] = W[tid + 256 * i];

    int row0 = blockIdx.x * 16;
    int r = tid >> 4, c4 = (tid & 15) << 2;
    int row = row0 + r;
    {
        float4 v = make_float4(0.f, 0.f, 0.f, 0.f);
        if (row < N) v = *(const float4*)(Xf + (size_t)row * DIM + c4);
        *(float4*)(Xs + r * DIM + c4) = v;
    }
    __syncthreads();

    float4 acc = make_float4(0.f, 0.f, 0.f, 0.f);
#pragma unroll
    for (int k = 0; k < 64; ++k) {
        float xk = Xs[r * DIM + k];
        float4 w = *(const float4*)(Ws + k * DIM + c4);
        acc.x += xk * w.x; acc.y += xk * w.y;
        acc.z += xk * w.z; acc.w += xk * w.w;
    }
    if (row < N) {
        float s = dinv[row];
        int p = 0;
        p = __builtin_amdgcn_cvt_pk_fp8_f32(acc.x * s, acc.y * s, p, false);
        p = __builtin_amdgcn_cvt_pk_fp8_f32(acc.z * s, acc.w * s, p, true);
        Y8[(size_t)row * 16 + (c4 >> 2)] = (unsigned int)p;
    } else if (row == N) {
        Y8[(size_t)row * 16 + (c4 >> 2)] = 0u;   // +0 in e4m3
    }
}

// ---------------- gather core: 16-lane group per node, 8 edges / 8 loads in flight ----------------
// lane l owns cols 4l..4l+3 (one uint of the fp8 row). Padding slots read row N (zeros).
// 32-bit offsets ((s<<4)|l) keep address math to one VALU op (saddr-form loads).

__device__ __forceinline__ float4 gather_rows(const unsigned int* __restrict__ hs8,
                                              const int* __restrict__ csr,
                                              int k0, int k1, int v, int l, int gw4,
                                              int N) {
    float4 a0, a1, a2, a3;
    {
        unsigned int u = hs8[(unsigned)((v << 4) | l)];    // self-loop term
        floatx2 f0 = __builtin_amdgcn_cvt_pk_f32_fp8((int)u, false);
        floatx2 f1 = __builtin_amdgcn_cvt_pk_f32_fp8((int)u, true);
        a0 = make_float4(f0.x, f0.y, f1.x, f1.y);
        a1 = make_float4(0.f, 0.f, 0.f, 0.f);
        a2 = make_float4(0.f, 0.f, 0.f, 0.f);
        a3 = make_float4(0.f, 0.f, 0.f, 0.f);
    }
    for (int kb = k0; kb < k1; kb += 16) {
        int rem = k1 - kb;
        int idx = (l < rem) ? csr[kb + l] : N;
        int mm = rem < 16 ? rem : 16;
        for (int j = 0; j < mm; j += 8) {
            int s0 = __shfl(idx, gw4 + j + 0);
            int s1 = __shfl(idx, gw4 + j + 1);
            int s2 = __shfl(idx, gw4 + j + 2);
            int s3 = __shfl(idx, gw4 + j + 3);
            int s4 = __shfl(idx, gw4 + j + 4);
            int s5 = __shfl(idx, gw4 + j + 5);
            int s6 = __shfl(idx, gw4 + j + 6);
            int s7 = __shfl(idx, gw4 + j + 7);
            unsigned int u0 = hs8[(unsigned)((s0 << 4) | l)];
            unsigned int u1 = hs8[(unsigned)((s1 << 4) | l)];
            unsigned int u2 = hs8[(unsigned)((s2 << 4) | l)];
            unsigned int u3 = hs8[(unsigned)((s3 << 4) | l)];
            unsigned int u4 = hs8[(unsigned)((s4 << 4) | l)];
            unsigned int u5 = hs8[(unsigned)((s5 << 4) | l)];
            unsigned int u6 = hs8[(unsigned)((s6 << 4) | l)];
            unsigned int u7 = hs8[(unsigned)((s7 << 4) | l)];
            floatx2 p0l = __builtin_amdgcn_cvt_pk_f32_fp8((int)u0, false);
            floatx2 p0h = __builtin_amdgcn_cvt_pk_f32_fp8((int)u0, true);
            floatx2 p1l = __builtin_amdgcn_cvt_pk_f32_fp8((int)u1, false);
            floatx2 p1h = __builtin_amdgcn_cvt_pk_f32_fp8((int)u1, true);
            floatx2 p2l = __builtin_amdgcn_cvt_pk_f32_fp8((int)u2, false);
            floatx2 p2h = __builtin_amdgcn_cvt_pk_f32_fp8((int)u2, true);
            floatx2 p3l = __builtin_amdgcn_cvt_pk_f32_fp8((int)u3, false);
            floatx2 p3h = __builtin_amdgcn_cvt_pk_f32_fp8((int)u3, true);
            floatx2 p4l = __builtin_amdgcn_cvt_pk_f32_fp8((int)u4, false);
            floatx2 p4h = __builtin_amdgcn_cvt_pk_f32_fp8((int)u4, true);
            floatx2 p5l = __builtin_amdgcn_cvt_pk_f32_fp8((int)u5, false);
            floatx2 p5h = __builtin_amdgcn_cvt_pk_f32_fp8((int)u5, true);
            floatx2 p6l = __builtin_amdgcn_cvt_pk_f32_fp8((int)u6, false);
            floatx2 p6h = __builtin_amdgcn_cvt_pk_f32_fp8((int)u6, true);
            floatx2 p7l = __builtin_amdgcn_cvt_pk_f32_fp8((int)u7, false);
            floatx2 p7h = __builtin_amdgcn_cvt_pk_f32_fp8((int)u7, true);
            a0.x += p0l.x; a0.y += p0l.y; a0.z += p0h.x; a0.w += p0h.y;
            a1.x += p1l.x; a1.y += p1l.y; a1.z += p1h.x; a1.w += p1h.y;
            a2.x += p2l.x; a2.y += p2l.y; a2.z += p2h.x; a2.w += p2h.y;
            a3.x += p3l.x; a3.y += p3l.y; a3.z += p3h.x; a3.w += p3h.y;
            a0.x += p4l.x; a0.y += p4l.y; a0.z += p4h.x; a0.w += p4h.y;
            a1.x += p5l.x; a1.y += p5l.y; a1.z += p5h.x; a1.w += p5h.y;
            a2.x += p6l.x; a2.y += p6l.y; a2.z += p6h.x; a2.w += p6h.y;
            a3.x += p7l.x; a3.y += p7l.y; a3.z += p7h.x; a3.w += p7h.y;
        }
    }
    return make_float4(a0.x + a1.x + a2.x + a3.x,
                       a0.y + a1.y + a2.y + a3.y,
                       a0.z + a1.z + a2.z + a3.z,
                       a0.w + a1.w + a2.w + a3.w);
}

// ---------------- fused gather + GEMM (layer 1 -> hs2 fp8 directly) ----------------
// block = 256 threads = 16 degree-balanced nodes (via nperm).

__global__ __launch_bounds__(256) void k_gather_gemm(const unsigned int* __restrict__ hs8,
                                                     const int* __restrict__ csr,
                                                     const int* __restrict__ off,
                                                     const int* __restrict__ nperm,
                                                     const float* __restrict__ dinv,
                                                     const float* __restrict__ bias,
                                                     const float* __restrict__ W,
                                                     unsigned int* __restrict__ hs_out,
                                                     int N) {
    __shared__ float Ws[64 * 64];
    __shared__ float Xs[16 * 64];
    int tid = threadIdx.x;
#pragma unroll
    for (int i = 0; i < 16; ++i) Ws[tid + 256 * i] = W[tid + 256 * i];
    if (blockIdx.x == 0 && tid < 16)
        hs_out[(size_t)N * 16 + tid] = 0u;               // zero pad row for gather2

    int r = tid >> 4;                                     // node slot in block
    int l = tid & 15;                                     // col-group (4 cols)
    int gw4 = ((tid >> 4) & 3) << 4;                      // group base lane within wave
    int v = nperm[blockIdx.x * 16 + r];

    float dv = 0.f;
    float4 h = make_float4(0.f, 0.f, 0.f, 0.f);
    if (v < N) {
        dv = dinv[v];
        float4 bv = ((const float4*)bias)[l];
        float4 acc = gather_rows(hs8, csr, off[v], off[v + 1], v, l, gw4, N);
        h.x = fmaxf(acc.x * dv + bv.x, 0.f);
        h.y = fmaxf(acc.y * dv + bv.y, 0.f);
        h.z = fmaxf(acc.z * dv + bv.z, 0.f);
        h.w = fmaxf(acc.w * dv + bv.w, 0.f);
    }
    *(float4*)(Xs + r * DIM + (l << 2)) = h;
    __syncthreads();

    float4 o = make_float4(0.f, 0.f, 0.f, 0.f);
#pragma unroll
    for (int k = 0; k < 64; ++k) {
        float xk = Xs[r * DIM + k];
        float4 w = *(const float4*)(Ws + k * DIM + (l << 2));
        o.x += xk * w.x; o.y += xk * w.y;
        o.z += xk * w.z; o.w += xk * w.w;
    }
    if (v < N) {
        int p = 0;
        p = __builtin_amdgcn_cvt_pk_fp8_f32(o.x * dv, o.y * dv, p, false);
        p = __builtin_amdgcn_cvt_pk_fp8_f32(o.z * dv, o.w * dv, p, true);
        hs_out[(size_t)v * 16 + l] = (unsigned int)p;
    }
}

// ---------------- gather (layer 2): fp16 agg output for pooling ----------------

__global__ __launch_bounds__(256) void k_gather16(const unsigned int* __restrict__ hs8,
                                                  const int* __restrict__ csr,
                                                  const int* __restrict__ off,
                                                  const int* __restrict__ nperm,
                                                  const float* __restrict__ dinv,
                                                  const float* __restrict__ bias,
                                                  __half* __restrict__ agg, int N) {
    int tid = threadIdx.x;
    int v = nperm[blockIdx.x * 16 + (tid >> 4)];
    if (v >= N) return;
    int l = tid & 15;
    int gw4 = ((tid >> 4) & 3) << 4;
    float dv = dinv[v];
    float4 bv = ((const float4*)bias)[l];
    float4 acc = gather_rows(hs8, csr, off[v], off[v + 1], v, l, gw4, N);
    __half2 p0 = __floats2half2_rn(acc.x * dv + bv.x, acc.y * dv + bv.y);
    __half2 p1 = __floats2half2_rn(acc.z * dv + bv.z, acc.w * dv + bv.w);
    uint2 u;
    u.x = *(unsigned int*)&p0;
    u.y = *(unsigned int*)&p1;
    ((uint2*)(agg + (size_t)v * DIM))[l] = u;
}

// ---------------- pool: out[g] = mean relu(agg2[v]) (fp16 input) ----------------

__global__ __launch_bounds__(256) void k_pool(const __half* __restrict__ agg,
                                              const int* __restrict__ goff,
                                              float* __restrict__ out, int G) {
    int g = blockIdx.x * 4 + (threadIdx.x >> 6);
    if (g >= G) return;
    int lane = threadIdx.x & 63;
    int q = lane >> 4, c = lane & 15;
    const uint2* h2 = (const uint2*)agg;
    int n0 = goff[g], n1 = goff[g + 1];
    float4 acc = make_float4(0.f, 0.f, 0.f, 0.f);
    for (int i = n0 + q; i < n1; i += 4) {
        uint2 u = h2[(size_t)i * 16 + c];
        float2 f0 = __half22float2(*(__half2*)&u.x);
        float2 f1 = __half22float2(*(__half2*)&u.y);
        acc.x += fmaxf(f0.x, 0.f); acc.y += fmaxf(f0.y, 0.f);
        acc.z += fmaxf(f1.x, 0.f); acc.w += fmaxf(f1.y, 0.f);
    }
    acc.x += __shfl_down(acc.x, 32); acc.y += __shfl_down(acc.y, 32);
    acc.z += __shfl_down(acc.z, 32); acc.w += __shfl_down(acc.w, 32);
    acc.x += __shfl_down(acc.x, 16); acc.y += __shfl_down(acc.y, 16);
    acc.z += __shfl_down(acc.z, 16); acc.w += __shfl_down(acc.w, 16);
    if (q == 0) {
        float inv = 1.0f / fmaxf((float)(n1 - n0), 1.0f);
        *(float4*)(out + ((size_t)g << 6) + (c << 2)) =
            make_float4(acc.x * inv, acc.y * inv, acc.z * inv, acc.w * inv);
    }
}

// ---------------- launch ----------------

static inline int cdiv(int a, int b) { return (a + b - 1) / b; }

extern "C" void kernel_launch(void* const* d_in, const int* in_sizes, int n_in,
                              void* d_out, int out_size, void* d_ws, size_t ws_size,
                              hipStream_t stream) {
    const float* x   = (const float*)d_in[0];
    const float* W1  = (const float*)d_in[1];
    const float* b1  = (const float*)d_in[2];
    const float* W2  = (const float*)d_in[3];
    const float* b2  = (const float*)d_in[4];
    const int*   ei  = (const int*)d_in[5];
    const int*   bat = (const int*)d_in[6];

    const int N = in_sizes[0] / DIM;
    const int E = in_sizes[5] / 2;
    const int G = out_size / DIM;
    const int NB = cdiv(N, BINSZ);           // <= MAXBINS
    const int M  = NB * PB;                  // scan length
    const int* src = ei;
    const int* dst = ei + E;
    float* out = (float*)d_out;

    // workspace: hs1 | hs2 | agg1 | dinv | off | goff | C | S | bsums | csr | nperm
    // bkt aliases hs1 (dead before gemm1); agg2 aliases hs1 region (dead after fused gather1).
    __half* hs1    = (__half*)d_ws;                         // (N+1)*64 h region
    __half* hs2    = hs1 + (size_t)(N + 1) * DIM;           // (N+1)*64 h region
    __half* agg1   = hs2 + (size_t)(N + 1) * DIM;           // N*64 h (unused)
    float*  dinv   = (float*)(agg1 + (size_t)N * DIM);      // N f
    int*    off    = (int*)(dinv + N);                      // N+1 i
    int*    goff   = off + (N + 1);                         // G+1 i
    int*    C      = goff + (G + 1);                        // PB*NB i
    int*    S      = C + (size_t)PB * NB;                   // PB*NB i
    int*    bsums  = S + (size_t)PB * NB;                   // up to 1024 i
    int*    csr    = bsums + 1024;                          // E i
    int*    nperm  = csr + E;                               // NB*BINSZ i
    int*    bkt    = (int*)hs1;                             // E i (aliased)
    __half* agg2   = hs1;                                   // N*64 h (aliased)

    k_hist<<<PB, 256, 0, stream>>>(dst, C, E, NB);
    int nb2 = cdiv(M, 4096);
    k_scanA<<<nb2, 1024, 0, stream>>>(C, S, bsums, NB, M);
    k_scanB<<<1, 1024, 0, stream>>>(bsums, nb2);
    k_bucket<<<PB, 256, 0, stream>>>(src, dst, S, bsums, bkt, E, NB);
    k_binsort<<<NB, 256, 0, stream>>>(bkt, S, bsums, csr, off, dinv, bat, goff,
                                      nperm, N, G, E, NB);

    // layer 1 transform: hs1 = (x @ W1) * dinv (fp8 e4m3)
    k_gemm<<<cdiv(N + 1, 16), 256, 0, stream>>>(x, W1, dinv, (unsigned int*)hs1, N);

    const int GGRID = NB * (BINSZ / 16);     // covers all nperm slots

    // fused: agg1 = gather(hs1)+b1 ; hs2 = (relu(agg1) @ W2) * dinv (fp8)
    k_gather_gemm<<<GGRID, 256, 0, stream>>>((const unsigned int*)hs1, csr, off, nperm,
                                             dinv, b1, W2, (unsigned int*)hs2, N);

    // layer 2 aggregate: agg2 = gather(hs2) + b2 (fp16, pre-relu)
    k_gather16<<<GGRID, 256, 0, stream>>>((const unsigned int*)hs2, csr, off, nperm,
                                          dinv, b2, agg2, N);

    k_pool<<<cdiv(G, 4), 256, 0, stream>>>(agg2, goff, out, G);
}

// Round 3
// 203.564 us; speedup vs baseline: 1.1401x; 1.1401x over previous
//
#include <hip/hip_runtime.h>
#include <hip/hip_fp16.h>

#define DIM 64
#define BIN_SHIFT 7
#define BINSZ 128      // nodes per bin
#define MAXBINS 1024   // supports N up to 131072
#define PB 512         // edge-slice blocks for hist/bucket (power of 2)
#define PB_LOG 9

typedef __attribute__((ext_vector_type(2))) float floatx2;
typedef __attribute__((ext_vector_type(4))) float f32x4;
typedef __attribute__((ext_vector_type(8))) _Float16 f16x8;
typedef __attribute__((ext_vector_type(4))) _Float16 f16x4;

// ---------------- pass 1: per-block LDS histogram -> C[blk][bin] ----------------

__global__ __launch_bounds__(256) void k_hist(const int* __restrict__ dst,
                                              int* __restrict__ C, int E, int NB) {
    __shared__ int h[MAXBINS];
    for (int i = threadIdx.x; i < NB; i += 256) h[i] = 0;
    __syncthreads();
    int per = (E + PB - 1) / PB;
    int e0 = blockIdx.x * per;
    int e1 = e0 + per; if (e1 > E) e1 = E;
    for (int e = e0 + (int)threadIdx.x; e < e1; e += 256)
        atomicAdd(&h[dst[e] >> BIN_SHIFT], 1);
    __syncthreads();
    for (int i = threadIdx.x; i < NB; i += 256)
        C[blockIdx.x * NB + i] = h[i];
}

// ---------------- pass 2a: chunk-local exclusive scan of C (bin-major order) ----------------

__global__ __launch_bounds__(1024) void k_scanA(const int* __restrict__ C,
                                                int* __restrict__ S,
                                                int* __restrict__ bsums, int NB, int M) {
    __shared__ int sh[1024];
    int tid = threadIdx.x;
    int j0 = blockIdx.x * 4096 + tid * 4;
    int v[4]; int sum = 0;
#pragma unroll
    for (int t = 0; t < 4; ++t) {
        int j = j0 + t; int x = 0;
        if (j < M) { int bin = j >> PB_LOG, blk = j & (PB - 1); x = C[blk * NB + bin]; }
        v[t] = sum; sum += x;
    }
    sh[tid] = sum;
    __syncthreads();
#pragma unroll
    for (int d = 1; d < 1024; d <<= 1) {
        int t = (tid >= d) ? sh[tid - d] : 0;
        __syncthreads();
        sh[tid] += t;
        __syncthreads();
    }
    int excl = sh[tid] - sum;
#pragma unroll
    for (int t = 0; t < 4; ++t) {
        int j = j0 + t;
        if (j < M) S[j] = excl + v[t];
    }
    if (tid == 1023) bsums[blockIdx.x] = sh[1023];
}

// ---------------- pass 2b: exclusive scan of chunk sums ----------------

__global__ __launch_bounds__(1024) void k_scanB(int* __restrict__ bsums, int nb) {
    __shared__ int s[1024];
    int tid = threadIdx.x;
    int v = (tid < nb) ? bsums[tid] : 0;
    s[tid] = v;
    __syncthreads();
#pragma unroll
    for (int d = 1; d < 1024; d <<= 1) {
        int t = (tid >= d) ? s[tid - d] : 0;
        __syncthreads();
        s[tid] += t;
        __syncthreads();
    }
    if (tid < nb) bsums[tid] = s[tid] - v;
}

// ---------------- pass 3: one-pass bucket scatter, LDS cursors ----------------

__global__ __launch_bounds__(256) void k_bucket(const int* __restrict__ src,
                                                const int* __restrict__ dst,
                                                const int* __restrict__ S,
                                                const int* __restrict__ bsums,
                                                int* __restrict__ bkt, int E, int NB) {
    __shared__ int lcur[MAXBINS];
    int blk = blockIdx.x;
    for (int i = threadIdx.x; i < NB; i += 256) {
        int j = i * PB + blk;
        lcur[i] = S[j] + bsums[j >> 12];
    }
    __syncthreads();
    int per = (E + PB - 1) / PB;
    int e0 = blk * per;
    int e1 = e0 + per; if (e1 > E) e1 = E;
    for (int e = e0 + (int)threadIdx.x; e < e1; e += 256) {
        int d = dst[e];
        int pos = atomicAdd(&lcur[d >> BIN_SHIFT], 1);
        bkt[pos] = src[e] | ((d & (BINSZ - 1)) << 24);
    }
}

// ---------------- pass 4: per-bin counting sort (shfl scan) -> csr, off, dinv; + gbound ----------------

__global__ __launch_bounds__(256) void k_binsort(const int* __restrict__ bkt,
                                                 const int* __restrict__ S,
                                                 const int* __restrict__ bsums,
                                                 int* __restrict__ csr,
                                                 int* __restrict__ off,
                                                 float* __restrict__ dinv,
                                                 const int* __restrict__ batch,
                                                 int* __restrict__ goff,
                                                 int N, int G, int E, int NB) {
    __shared__ int cnt[BINSZ], bas[BINSZ], cur[BINSZ];
    __shared__ int wsum[4];
    int tid = threadIdx.x;
    int b = blockIdx.x;
    int j0 = b << PB_LOG;
    int s0 = S[j0] + bsums[j0 >> 12];
    int s1 = E;
    if (b + 1 < NB) { int j1 = (b + 1) << PB_LOG; s1 = S[j1] + bsums[j1 >> 12]; }
    if (tid < BINSZ) { cnt[tid] = 0; cur[tid] = 0; }
    __syncthreads();
    for (int i = s0 + tid; i < s1; i += 256)
        atomicAdd(&cnt[(bkt[i] >> 24) & (BINSZ - 1)], 1);
    __syncthreads();
    int my = (tid < BINSZ) ? cnt[tid] : 0;
    int lane = tid & 63, wv = tid >> 6;
    int x = my;
#pragma unroll
    for (int d = 1; d < 64; d <<= 1) {
        int t = __shfl_up(x, d);
        if (lane >= d) x += t;
    }
    if (lane == 63) wsum[wv] = x;
    __syncthreads();
    int prefix = 0;
    for (int w = 0; w < wv; ++w) prefix += wsum[w];
    int ex = x + prefix - my;               // exclusive base
    if (tid < BINSZ) {
        bas[tid] = ex;
        int v = (b << BIN_SHIFT) + tid;
        if (v < N) {
            off[v] = s0 + ex;
            dinv[v] = rsqrtf((float)(my + 1));   // +1 self-loop
            if (v == N - 1) off[N] = E;
            // fused gbound (batch sorted)
            int bb = batch[v];
            int prev = (v == 0) ? -1 : batch[v - 1];
            for (int g = prev + 1; g <= bb; ++g) goff[g] = v;
            if (v == N - 1)
                for (int g = bb + 1; g <= G; ++g) goff[g] = N;
        }
    }
    __syncthreads();
    for (int i = s0 + tid; i < s1; i += 256) {
        int p = bkt[i];
        int lo = (p >> 24) & (BINSZ - 1);
        int li = atomicAdd(&cur[lo], 1);
        csr[s0 + bas[lo] + li] = p & 0xFFFFFF;
    }
}

// ---------------- skinny GEMM via MFMA: hs[row] = (X[row] @ W) * dinv[row], fp8 out ----------------
// Wave w of each block computes the 16-row x 16-col tile at cols [16w,16w+16).
// k-map bijection: k = 32s + 8*(lane>>4) + elem, applied to BOTH A and B fragments.
// D layout (HW-verified): col = lane&15, row = 4*(lane>>4) + reg.

__global__ __launch_bounds__(256) void k_gemm(const float* __restrict__ X,
                                              const float* __restrict__ W,
                                              const float* __restrict__ dinv,
                                              unsigned int* __restrict__ Y8, int N) {
    __shared__ float Os[16 * 68];
    int tid = threadIdx.x;
    int lane = tid & 63, w = tid >> 6;
    int m = lane & 15, g = lane >> 4;
    int row0 = blockIdx.x * 16;
    int row = row0 + m;

    // B fragments from global W (row-major [k][n]); L1-hot
    f16x8 B0, B1;
    {
        int n = (w << 4) + m;
        const float* wp = W + (g << 3) * 64 + n;
#pragma unroll
        for (int j = 0; j < 8; ++j) B0[j] = (_Float16)wp[j * 64];
        wp += 32 * 64;
#pragma unroll
        for (int j = 0; j < 8; ++j) B1[j] = (_Float16)wp[j * 64];
    }
    // A fragments straight from global X
    f16x8 A0, A1;
    {
        float4 u0 = make_float4(0.f, 0.f, 0.f, 0.f), u1 = u0, u2 = u0, u3 = u0;
        if (row < N) {
            const float* xp = X + (size_t)row * DIM + (g << 3);
            u0 = *(const float4*)(xp);
            u1 = *(const float4*)(xp + 4);
            u2 = *(const float4*)(xp + 32);
            u3 = *(const float4*)(xp + 36);
        }
        A0[0] = (_Float16)u0.x; A0[1] = (_Float16)u0.y; A0[2] = (_Float16)u0.z; A0[3] = (_Float16)u0.w;
        A0[4] = (_Float16)u1.x; A0[5] = (_Float16)u1.y; A0[6] = (_Float16)u1.z; A0[7] = (_Float16)u1.w;
        A1[0] = (_Float16)u2.x; A1[1] = (_Float16)u2.y; A1[2] = (_Float16)u2.z; A1[3] = (_Float16)u2.w;
        A1[4] = (_Float16)u3.x; A1[5] = (_Float16)u3.y; A1[6] = (_Float16)u3.z; A1[7] = (_Float16)u3.w;
    }
    f32x4 acc = {0.f, 0.f, 0.f, 0.f};
    acc = __builtin_amdgcn_mfma_f32_16x16x32_f16(A0, B0, acc, 0, 0, 0);
    acc = __builtin_amdgcn_mfma_f32_16x16x32_f16(A1, B1, acc, 0, 0, 0);
#pragma unroll
    for (int j = 0; j < 4; ++j)
        Os[((g << 2) + j) * 68 + (w << 4) + m] = acc[j];
    __syncthreads();

    int r = tid >> 4, c = tid & 15;
    int orow = row0 + r;
    if (orow < N) {
        float4 o = *(const float4*)(Os + r * 68 + (c << 2));
        float s = dinv[orow];
        int p = 0;
        p = __builtin_amdgcn_cvt_pk_fp8_f32(o.x * s, o.y * s, p, false);
        p = __builtin_amdgcn_cvt_pk_fp8_f32(o.z * s, o.w * s, p, true);
        Y8[(size_t)orow * 16 + c] = (unsigned int)p;
    } else if (orow == N) {
        Y8[(size_t)orow * 16 + c] = 0u;   // +0 in e4m3 (gather pad row)
    }
}

// ---------------- gather core: 16-lane group per node, 8 edges / 8 loads in flight ----------------
// lane l owns cols 4l..4l+3 (one uint of the fp8 row). Padding slots read row N (zeros).

__device__ __forceinline__ float4 gather_rows(const unsigned int* __restrict__ hs8,
                                              const int* __restrict__ csr,
                                              int k0, int k1, int v, int l, int gw4,
                                              int N) {
    float4 a0, a1, a2, a3;
    {
        unsigned int u = hs8[(unsigned)((v << 4) | l)];    // self-loop term
        floatx2 f0 = __builtin_amdgcn_cvt_pk_f32_fp8((int)u, false);
        floatx2 f1 = __builtin_amdgcn_cvt_pk_f32_fp8((int)u, true);
        a0 = make_float4(f0.x, f0.y, f1.x, f1.y);
        a1 = make_float4(0.f, 0.f, 0.f, 0.f);
        a2 = make_float4(0.f, 0.f, 0.f, 0.f);
        a3 = make_float4(0.f, 0.f, 0.f, 0.f);
    }
    for (int kb = k0; kb < k1; kb += 16) {
        int rem = k1 - kb;
        int idx = (l < rem) ? csr[kb + l] : N;
        int mm = rem < 16 ? rem : 16;
        for (int j = 0; j < mm; j += 8) {
            int s0 = __shfl(idx, gw4 + j + 0);
            int s1 = __shfl(idx, gw4 + j + 1);
            int s2 = __shfl(idx, gw4 + j + 2);
            int s3 = __shfl(idx, gw4 + j + 3);
            int s4 = __shfl(idx, gw4 + j + 4);
            int s5 = __shfl(idx, gw4 + j + 5);
            int s6 = __shfl(idx, gw4 + j + 6);
            int s7 = __shfl(idx, gw4 + j + 7);
            unsigned int u0 = hs8[(unsigned)((s0 << 4) | l)];
            unsigned int u1 = hs8[(unsigned)((s1 << 4) | l)];
            unsigned int u2 = hs8[(unsigned)((s2 << 4) | l)];
            unsigned int u3 = hs8[(unsigned)((s3 << 4) | l)];
            unsigned int u4 = hs8[(unsigned)((s4 << 4) | l)];
            unsigned int u5 = hs8[(unsigned)((s5 << 4) | l)];
            unsigned int u6 = hs8[(unsigned)((s6 << 4) | l)];
            unsigned int u7 = hs8[(unsigned)((s7 << 4) | l)];
            floatx2 p0l = __builtin_amdgcn_cvt_pk_f32_fp8((int)u0, false);
            floatx2 p0h = __builtin_amdgcn_cvt_pk_f32_fp8((int)u0, true);
            floatx2 p1l = __builtin_amdgcn_cvt_pk_f32_fp8((int)u1, false);
            floatx2 p1h = __builtin_amdgcn_cvt_pk_f32_fp8((int)u1, true);
            floatx2 p2l = __builtin_amdgcn_cvt_pk_f32_fp8((int)u2, false);
            floatx2 p2h = __builtin_amdgcn_cvt_pk_f32_fp8((int)u2, true);
            floatx2 p3l = __builtin_amdgcn_cvt_pk_f32_fp8((int)u3, false);
            floatx2 p3h = __builtin_amdgcn_cvt_pk_f32_fp8((int)u3, true);
            floatx2 p4l = __builtin_amdgcn_cvt_pk_f32_fp8((int)u4, false);
            floatx2 p4h = __builtin_amdgcn_cvt_pk_f32_fp8((int)u4, true);
            floatx2 p5l = __builtin_amdgcn_cvt_pk_f32_fp8((int)u5, false);
            floatx2 p5h = __builtin_amdgcn_cvt_pk_f32_fp8((int)u5, true);
            floatx2 p6l = __builtin_amdgcn_cvt_pk_f32_fp8((int)u6, false);
            floatx2 p6h = __builtin_amdgcn_cvt_pk_f32_fp8((int)u6, true);
            floatx2 p7l = __builtin_amdgcn_cvt_pk_f32_fp8((int)u7, false);
            floatx2 p7h = __builtin_amdgcn_cvt_pk_f32_fp8((int)u7, true);
            a0.x += p0l.x; a0.y += p0l.y; a0.z += p0h.x; a0.w += p0h.y;
            a1.x += p1l.x; a1.y += p1l.y; a1.z += p1h.x; a1.w += p1h.y;
            a2.x += p2l.x; a2.y += p2l.y; a2.z += p2h.x; a2.w += p2h.y;
            a3.x += p3l.x; a3.y += p3l.y; a3.z += p3h.x; a3.w += p3h.y;
            a0.x += p4l.x; a0.y += p4l.y; a0.z += p4h.x; a0.w += p4h.y;
            a1.x += p5l.x; a1.y += p5l.y; a1.z += p5h.x; a1.w += p5h.y;
            a2.x += p6l.x; a2.y += p6l.y; a2.z += p6h.x; a2.w += p6h.y;
            a3.x += p7l.x; a3.y += p7l.y; a3.z += p7h.x; a3.w += p7h.y;
        }
    }
    return make_float4(a0.x + a1.x + a2.x + a3.x,
                       a0.y + a1.y + a2.y + a3.y,
                       a0.z + a1.z + a2.z + a3.z,
                       a0.w + a1.w + a2.w + a3.w);
}

// ---------------- fused gather + MFMA GEMM (layer 1 -> hs2 fp8 directly) ----------------
// block = 256 threads = 16 nodes. gathered row relu'd into fp16 LDS tile, MFMA vs W2
// fragments (built from global, no W LDS), fp32 epilogue transpose via Os, fp8 out.

__global__ __launch_bounds__(256) void k_gather_gemm(const unsigned int* __restrict__ hs8,
                                                     const int* __restrict__ csr,
                                                     const int* __restrict__ off,
                                                     const float* __restrict__ dinv,
                                                     const float* __restrict__ bias,
                                                     const float* __restrict__ W,
                                                     unsigned int* __restrict__ hs_out,
                                                     int N) {
    __shared__ _Float16 Xs[16 * 72];
    __shared__ float Os[16 * 68];
    int tid = threadIdx.x;
    int r = tid >> 4, l = tid & 15;
    int lane = tid & 63, w = tid >> 6;
    int m = lane & 15, g = lane >> 4;
    int gw4 = (r & 3) << 4;
    int v = blockIdx.x * 16 + r;

    // B fragments first (global-load latency overlaps the gather)
    f16x8 B0, B1;
    {
        int n = (w << 4) + m;
        const float* wp = W + (g << 3) * 64 + n;
#pragma unroll
        for (int j = 0; j < 8; ++j) B0[j] = (_Float16)wp[j * 64];
        wp += 32 * 64;
#pragma unroll
        for (int j = 0; j < 8; ++j) B1[j] = (_Float16)wp[j * 64];
    }
    if (blockIdx.x == 0 && tid < 16)
        hs_out[(size_t)N * 16 + tid] = 0u;               // zero pad row for gather2

    float dv = 0.f;
    float4 h = make_float4(0.f, 0.f, 0.f, 0.f);
    if (v < N) {
        dv = dinv[v];
        float4 bv = ((const float4*)bias)[l];
        float4 acc = gather_rows(hs8, csr, off[v], off[v + 1], v, l, gw4, N);
        h.x = fmaxf(acc.x * dv + bv.x, 0.f);
        h.y = fmaxf(acc.y * dv + bv.y, 0.f);
        h.z = fmaxf(acc.z * dv + bv.z, 0.f);
        h.w = fmaxf(acc.w * dv + bv.w, 0.f);
    }
    {
        f16x4 hv;
        hv[0] = (_Float16)h.x; hv[1] = (_Float16)h.y;
        hv[2] = (_Float16)h.z; hv[3] = (_Float16)h.w;
        *(f16x4*)(Xs + r * 72 + (l << 2)) = hv;
    }
    __syncthreads();

    f16x8 A0 = *(const f16x8*)(Xs + m * 72 + (g << 3));
    f16x8 A1 = *(const f16x8*)(Xs + m * 72 + 32 + (g << 3));
    f32x4 acc2 = {0.f, 0.f, 0.f, 0.f};
    acc2 = __builtin_amdgcn_mfma_f32_16x16x32_f16(A0, B0, acc2, 0, 0, 0);
    acc2 = __builtin_amdgcn_mfma_f32_16x16x32_f16(A1, B1, acc2, 0, 0, 0);
#pragma unroll
    for (int j = 0; j < 4; ++j)
        Os[((g << 2) + j) * 68 + (w << 4) + m] = acc2[j];
    __syncthreads();

    if (v < N) {
        float4 o = *(const float4*)(Os + r * 68 + (l << 2));
        int p = 0;
        p = __builtin_amdgcn_cvt_pk_fp8_f32(o.x * dv, o.y * dv, p, false);
        p = __builtin_amdgcn_cvt_pk_fp8_f32(o.z * dv, o.w * dv, p, true);
        hs_out[(size_t)v * 16 + l] = (unsigned int)p;
    }
}

// ---------------- gather (layer 2): fp16 agg output for pooling ----------------

__global__ __launch_bounds__(256) void k_gather16(const unsigned int* __restrict__ hs8,
                                                  const int* __restrict__ csr,
                                                  const int* __restrict__ off,
                                                  const float* __restrict__ dinv,
                                                  const float* __restrict__ bias,
                                                  __half* __restrict__ agg, int N) {
    int tid = threadIdx.x;
    int v = blockIdx.x * 16 + (tid >> 4);
    if (v >= N) return;
    int l = tid & 15;
    int gw4 = ((tid >> 4) & 3) << 4;
    float dv = dinv[v];
    float4 bv = ((const float4*)bias)[l];
    float4 acc = gather_rows(hs8, csr, off[v], off[v + 1], v, l, gw4, N);
    __half2 p0 = __floats2half2_rn(acc.x * dv + bv.x, acc.y * dv + bv.y);
    __half2 p1 = __floats2half2_rn(acc.z * dv + bv.z, acc.w * dv + bv.w);
    uint2 u;
    u.x = *(unsigned int*)&p0;
    u.y = *(unsigned int*)&p1;
    ((uint2*)(agg + (size_t)v * DIM))[l] = u;
}

// ---------------- pool: out[g] = mean relu(agg2[v]) (fp16 input) ----------------

__global__ __launch_bounds__(256) void k_pool(const __half* __restrict__ agg,
                                              const int* __restrict__ goff,
                                              float* __restrict__ out, int G) {
    int g = blockIdx.x * 4 + (threadIdx.x >> 6);
    if (g >= G) return;
    int lane = threadIdx.x & 63;
    int q = lane >> 4, c = lane & 15;
    const uint2* h2 = (const uint2*)agg;
    int n0 = goff[g], n1 = goff[g + 1];
    float4 acc = make_float4(0.f, 0.f, 0.f, 0.f);
    for (int i = n0 + q; i < n1; i += 4) {
        uint2 u = h2[(size_t)i * 16 + c];
        float2 f0 = __half22float2(*(__half2*)&u.x);
        float2 f1 = __half22float2(*(__half2*)&u.y);
        acc.x += fmaxf(f0.x, 0.f); acc.y += fmaxf(f0.y, 0.f);
        acc.z += fmaxf(f1.x, 0.f); acc.w += fmaxf(f1.y, 0.f);
    }
    acc.x += __shfl_down(acc.x, 32); acc.y += __shfl_down(acc.y, 32);
    acc.z += __shfl_down(acc.z, 32); acc.w += __shfl_down(acc.w, 32);
    acc.x += __shfl_down(acc.x, 16); acc.y += __shfl_down(acc.y, 16);
    acc.z += __shfl_down(acc.z, 16); acc.w += __shfl_down(acc.w, 16);
    if (q == 0) {
        float inv = 1.0f / fmaxf((float)(n1 - n0), 1.0f);
        *(float4*)(out + ((size_t)g << 6) + (c << 2)) =
            make_float4(acc.x * inv, acc.y * inv, acc.z * inv, acc.w * inv);
    }
}

// ---------------- launch ----------------

static inline int cdiv(int a, int b) { return (a + b - 1) / b; }

extern "C" void kernel_launch(void* const* d_in, const int* in_sizes, int n_in,
                              void* d_out, int out_size, void* d_ws, size_t ws_size,
                              hipStream_t stream) {
    const float* x   = (const float*)d_in[0];
    const float* W1  = (const float*)d_in[1];
    const float* b1  = (const float*)d_in[2];
    const float* W2  = (const float*)d_in[3];
    const float* b2  = (const float*)d_in[4];
    const int*   ei  = (const int*)d_in[5];
    const int*   bat = (const int*)d_in[6];

    const int N = in_sizes[0] / DIM;
    const int E = in_sizes[5] / 2;
    const int G = out_size / DIM;
    const int NB = cdiv(N, BINSZ);           // <= MAXBINS
    const int M  = NB * PB;                  // scan length
    const int* src = ei;
    const int* dst = ei + E;
    float* out = (float*)d_out;

    // workspace: hs1 | hs2 | agg1 | dinv | off | goff | C | S | bsums | csr
    // bkt aliases hs1 (dead before gemm1); agg2 aliases hs1 region (dead after fused gather1).
    __half* hs1    = (__half*)d_ws;                         // (N+1)*64 h region
    __half* hs2    = hs1 + (size_t)(N + 1) * DIM;           // (N+1)*64 h region
    __half* agg1   = hs2 + (size_t)(N + 1) * DIM;           // N*64 h (unused)
    float*  dinv   = (float*)(agg1 + (size_t)N * DIM);      // N f
    int*    off    = (int*)(dinv + N);                      // N+1 i
    int*    goff   = off + (N + 1);                         // G+1 i
    int*    C      = goff + (G + 1);                        // PB*NB i
    int*    S      = C + (size_t)PB * NB;                   // PB*NB i
    int*    bsums  = S + (size_t)PB * NB;                   // up to 1024 i
    int*    csr    = bsums + 1024;                          // E i
    int*    bkt    = (int*)hs1;                             // E i (aliased)
    __half* agg2   = hs1;                                   // N*64 h (aliased)

    k_hist<<<PB, 256, 0, stream>>>(dst, C, E, NB);
    int nb2 = cdiv(M, 4096);
    k_scanA<<<nb2, 1024, 0, stream>>>(C, S, bsums, NB, M);
    k_scanB<<<1, 1024, 0, stream>>>(bsums, nb2);
    k_bucket<<<PB, 256, 0, stream>>>(src, dst, S, bsums, bkt, E, NB);
    k_binsort<<<NB, 256, 0, stream>>>(bkt, S, bsums, csr, off, dinv, bat, goff, N, G, E, NB);

    // layer 1 transform: hs1 = (x @ W1) * dinv (fp8 e4m3), MFMA
    k_gemm<<<cdiv(N + 1, 16), 256, 0, stream>>>(x, W1, dinv, (unsigned int*)hs1, N);

    // fused: agg1 = gather(hs1)+b1 ; hs2 = (relu(agg1) @ W2) * dinv (fp8), MFMA
    k_gather_gemm<<<cdiv(N, 16), 256, 0, stream>>>((const unsigned int*)hs1, csr, off,
                                                   dinv, b1, W2, (unsigned int*)hs2, N);

    // layer 2 aggregate: agg2 = gather(hs2) + b2 (fp16, pre-relu)
    k_gather16<<<cdiv(N, 16), 256, 0, stream>>>((const unsigned int*)hs2, csr, off,
                                                dinv, b2, agg2, N);

    k_pool<<<cdiv(G, 4), 256, 0, stream>>>(agg2, goff, out, G);
}

// Round 4
// 197.194 us; speedup vs baseline: 1.1769x; 1.0323x over previous
//
#include <hip/hip_runtime.h>
#include <hip/hip_fp16.h>

#define DIM 64
#define BIN_SHIFT 7
#define BINSZ 128      // nodes per bin
#define MAXBINS 1024   // supports N up to 131072
#define PB 512         // edge-slice blocks for hist/bucket (power of 2)
#define PB_LOG 9

typedef __attribute__((ext_vector_type(2))) float floatx2;
typedef __attribute__((ext_vector_type(4))) float f32x4;
typedef __attribute__((ext_vector_type(8))) _Float16 f16x8;
typedef __attribute__((ext_vector_type(4))) _Float16 f16x4;

// ---------------- pass 1: per-block LDS histogram -> C[blk][bin] ----------------

__global__ __launch_bounds__(256) void k_hist(const int* __restrict__ dst,
                                              int* __restrict__ C, int E, int NB) {
    __shared__ int h[MAXBINS];
    for (int i = threadIdx.x; i < NB; i += 256) h[i] = 0;
    __syncthreads();
    int per = (E + PB - 1) / PB;
    int e0 = blockIdx.x * per;
    int e1 = e0 + per; if (e1 > E) e1 = E;
    for (int e = e0 + (int)threadIdx.x; e < e1; e += 256)
        atomicAdd(&h[dst[e] >> BIN_SHIFT], 1);
    __syncthreads();
    for (int i = threadIdx.x; i < NB; i += 256)
        C[blockIdx.x * NB + i] = h[i];
}

// ---------------- pass 2a: chunk-local exclusive scan of C (bin-major order) ----------------

__global__ __launch_bounds__(1024) void k_scanA(const int* __restrict__ C,
                                                int* __restrict__ S,
                                                int* __restrict__ bsums, int NB, int M) {
    __shared__ int sh[1024];
    int tid = threadIdx.x;
    int j0 = blockIdx.x * 4096 + tid * 4;
    int v[4]; int sum = 0;
#pragma unroll
    for (int t = 0; t < 4; ++t) {
        int j = j0 + t; int x = 0;
        if (j < M) { int bin = j >> PB_LOG, blk = j & (PB - 1); x = C[blk * NB + bin]; }
        v[t] = sum; sum += x;
    }
    sh[tid] = sum;
    __syncthreads();
#pragma unroll
    for (int d = 1; d < 1024; d <<= 1) {
        int t = (tid >= d) ? sh[tid - d] : 0;
        __syncthreads();
        sh[tid] += t;
        __syncthreads();
    }
    int excl = sh[tid] - sum;
#pragma unroll
    for (int t = 0; t < 4; ++t) {
        int j = j0 + t;
        if (j < M) S[j] = excl + v[t];
    }
    if (tid == 1023) bsums[blockIdx.x] = sh[1023];
}

// ---------------- pass 2b: exclusive scan of chunk sums ----------------

__global__ __launch_bounds__(1024) void k_scanB(int* __restrict__ bsums, int nb) {
    __shared__ int s[1024];
    int tid = threadIdx.x;
    int v = (tid < nb) ? bsums[tid] : 0;
    s[tid] = v;
    __syncthreads();
#pragma unroll
    for (int d = 1; d < 1024; d <<= 1) {
        int t = (tid >= d) ? s[tid - d] : 0;
        __syncthreads();
        s[tid] += t;
        __syncthreads();
    }
    if (tid < nb) bsums[tid] = s[tid] - v;
}

// ---------------- pass 3: one-pass bucket scatter, LDS cursors ----------------

__global__ __launch_bounds__(256) void k_bucket(const int* __restrict__ src,
                                                const int* __restrict__ dst,
                                                const int* __restrict__ S,
                                                const int* __restrict__ bsums,
                                                int* __restrict__ bkt, int E, int NB) {
    __shared__ int lcur[MAXBINS];
    int blk = blockIdx.x;
    for (int i = threadIdx.x; i < NB; i += 256) {
        int j = i * PB + blk;
        lcur[i] = S[j] + bsums[j >> 12];
    }
    __syncthreads();
    int per = (E + PB - 1) / PB;
    int e0 = blk * per;
    int e1 = e0 + per; if (e1 > E) e1 = E;
    for (int e = e0 + (int)threadIdx.x; e < e1; e += 256) {
        int d = dst[e];
        int pos = atomicAdd(&lcur[d >> BIN_SHIFT], 1);
        bkt[pos] = src[e] | ((d & (BINSZ - 1)) << 24);
    }
}

// ---------------- pass 4: per-bin counting sort -> csr, off, dinv; + gbound; + zero out ----------------

__global__ __launch_bounds__(256) void k_binsort(const int* __restrict__ bkt,
                                                 const int* __restrict__ S,
                                                 const int* __restrict__ bsums,
                                                 int* __restrict__ csr,
                                                 int* __restrict__ off,
                                                 float* __restrict__ dinv,
                                                 const int* __restrict__ batch,
                                                 int* __restrict__ goff,
                                                 float* __restrict__ outz,
                                                 int N, int G, int E, int NB) {
    __shared__ int cnt[BINSZ], bas[BINSZ], cur[BINSZ];
    __shared__ int wsum[4];
    int tid = threadIdx.x;
    int b = blockIdx.x;
    // zero the pooled output (k_gather_pool accumulates via atomics)
    for (int i = b * 256 + tid; i < G * DIM; i += NB * 256) outz[i] = 0.f;
    int j0 = b << PB_LOG;
    int s0 = S[j0] + bsums[j0 >> 12];
    int s1 = E;
    if (b + 1 < NB) { int j1 = (b + 1) << PB_LOG; s1 = S[j1] + bsums[j1 >> 12]; }
    if (tid < BINSZ) { cnt[tid] = 0; cur[tid] = 0; }
    __syncthreads();
    for (int i = s0 + tid; i < s1; i += 256)
        atomicAdd(&cnt[(bkt[i] >> 24) & (BINSZ - 1)], 1);
    __syncthreads();
    int my = (tid < BINSZ) ? cnt[tid] : 0;
    int lane = tid & 63, wv = tid >> 6;
    int x = my;
#pragma unroll
    for (int d = 1; d < 64; d <<= 1) {
        int t = __shfl_up(x, d);
        if (lane >= d) x += t;
    }
    if (lane == 63) wsum[wv] = x;
    __syncthreads();
    int prefix = 0;
    for (int w = 0; w < wv; ++w) prefix += wsum[w];
    int ex = x + prefix - my;               // exclusive base
    if (tid < BINSZ) {
        bas[tid] = ex;
        int v = (b << BIN_SHIFT) + tid;
        if (v < N) {
            off[v] = s0 + ex;
            dinv[v] = rsqrtf((float)(my + 1));   // +1 self-loop
            if (v == N - 1) off[N] = E;
            // fused gbound (batch sorted)
            int bb = batch[v];
            int prev = (v == 0) ? -1 : batch[v - 1];
            for (int g = prev + 1; g <= bb; ++g) goff[g] = v;
            if (v == N - 1)
                for (int g = bb + 1; g <= G; ++g) goff[g] = N;
        }
    }
    __syncthreads();
    for (int i = s0 + tid; i < s1; i += 256) {
        int p = bkt[i];
        int lo = (p >> 24) & (BINSZ - 1);
        int li = atomicAdd(&cur[lo], 1);
        csr[s0 + bas[lo] + li] = p & 0xFFFFFF;
    }
}

// ---------------- skinny GEMM via MFMA: hs[row] = (X[row] @ W) * dinv[row], fp8 out ----------------
// Wave w computes the 16-row x 16-col tile at cols [16w,16w+16).
// k-map bijection: k = 32s + 8*(lane>>4) + elem, applied to BOTH A and B fragments.
// D layout (HW-verified): col = lane&15, row = 4*(lane>>4) + reg.

__global__ __launch_bounds__(256) void k_gemm(const float* __restrict__ X,
                                              const float* __restrict__ W,
                                              const float* __restrict__ dinv,
                                              unsigned int* __restrict__ Y8, int N) {
    __shared__ float Os[16 * 68];
    int tid = threadIdx.x;
    int lane = tid & 63, w = tid >> 6;
    int m = lane & 15, g = lane >> 4;
    int row0 = blockIdx.x * 16;
    int row = row0 + m;

    // B fragments from global W (row-major [k][n]); L1-hot
    f16x8 B0, B1;
    {
        int n = (w << 4) + m;
        const float* wp = W + (g << 3) * 64 + n;
#pragma unroll
        for (int j = 0; j < 8; ++j) B0[j] = (_Float16)wp[j * 64];
        wp += 32 * 64;
#pragma unroll
        for (int j = 0; j < 8; ++j) B1[j] = (_Float16)wp[j * 64];
    }
    // A fragments straight from global X
    f16x8 A0, A1;
    {
        float4 u0 = make_float4(0.f, 0.f, 0.f, 0.f), u1 = u0, u2 = u0, u3 = u0;
        if (row < N) {
            const float* xp = X + (size_t)row * DIM + (g << 3);
            u0 = *(const float4*)(xp);
            u1 = *(const float4*)(xp + 4);
            u2 = *(const float4*)(xp + 32);
            u3 = *(const float4*)(xp + 36);
        }
        A0[0] = (_Float16)u0.x; A0[1] = (_Float16)u0.y; A0[2] = (_Float16)u0.z; A0[3] = (_Float16)u0.w;
        A0[4] = (_Float16)u1.x; A0[5] = (_Float16)u1.y; A0[6] = (_Float16)u1.z; A0[7] = (_Float16)u1.w;
        A1[0] = (_Float16)u2.x; A1[1] = (_Float16)u2.y; A1[2] = (_Float16)u2.z; A1[3] = (_Float16)u2.w;
        A1[4] = (_Float16)u3.x; A1[5] = (_Float16)u3.y; A1[6] = (_Float16)u3.z; A1[7] = (_Float16)u3.w;
    }
    f32x4 acc = {0.f, 0.f, 0.f, 0.f};
    acc = __builtin_amdgcn_mfma_f32_16x16x32_f16(A0, B0, acc, 0, 0, 0);
    acc = __builtin_amdgcn_mfma_f32_16x16x32_f16(A1, B1, acc, 0, 0, 0);
#pragma unroll
    for (int j = 0; j < 4; ++j)
        Os[((g << 2) + j) * 68 + (w << 4) + m] = acc[j];
    __syncthreads();

    int r = tid >> 4, c = tid & 15;
    int orow = row0 + r;
    if (orow < N) {
        float4 o = *(const float4*)(Os + r * 68 + (c << 2));
        float s = dinv[orow];
        int p = 0;
        p = __builtin_amdgcn_cvt_pk_fp8_f32(o.x * s, o.y * s, p, false);
        p = __builtin_amdgcn_cvt_pk_fp8_f32(o.z * s, o.w * s, p, true);
        Y8[(size_t)orow * 16 + c] = (unsigned int)p;
    } else if (orow == N) {
        Y8[(size_t)orow * 16 + c] = 0u;   // +0 in e4m3 (gather pad row)
    }
}

// ---------------- gather core: 16-lane group per node, 16 edges / 16 loads in flight ----------------
// lane l owns cols 4l..4l+3 (one uint of the fp8 row). Padding slots read row N (zeros,
// single broadcast cacheline). All 16 loads issued before any conversion -> 1 latency
// exposure per 16-edge chunk.

__device__ __forceinline__ float4 gather_rows(const unsigned int* __restrict__ hs8,
                                              const int* __restrict__ csr,
                                              int k0, int k1, int v, int l, int gw4,
                                              int N) {
    float4 a0, a1, a2, a3;
    {
        unsigned int u = hs8[(unsigned)((v << 4) | l)];    // self-loop term
        floatx2 f0 = __builtin_amdgcn_cvt_pk_f32_fp8((int)u, false);
        floatx2 f1 = __builtin_amdgcn_cvt_pk_f32_fp8((int)u, true);
        a0 = make_float4(f0.x, f0.y, f1.x, f1.y);
        a1 = make_float4(0.f, 0.f, 0.f, 0.f);
        a2 = make_float4(0.f, 0.f, 0.f, 0.f);
        a3 = make_float4(0.f, 0.f, 0.f, 0.f);
    }
    for (int kb = k0; kb < k1; kb += 16) {
        int rem = k1 - kb;
        int idx = (l < rem) ? csr[kb + l] : N;
        unsigned uu[16];
#pragma unroll
        for (int t = 0; t < 16; ++t) {
            int s = __shfl(idx, gw4 + t);
            uu[t] = hs8[(unsigned)((s << 4) | l)];
        }
#pragma unroll
        for (int t = 0; t < 16; t += 4) {
            floatx2 q0 = __builtin_amdgcn_cvt_pk_f32_fp8((int)uu[t + 0], false);
            floatx2 q1 = __builtin_amdgcn_cvt_pk_f32_fp8((int)uu[t + 0], true);
            floatx2 q2 = __builtin_amdgcn_cvt_pk_f32_fp8((int)uu[t + 1], false);
            floatx2 q3 = __builtin_amdgcn_cvt_pk_f32_fp8((int)uu[t + 1], true);
            floatx2 q4 = __builtin_amdgcn_cvt_pk_f32_fp8((int)uu[t + 2], false);
            floatx2 q5 = __builtin_amdgcn_cvt_pk_f32_fp8((int)uu[t + 2], true);
            floatx2 q6 = __builtin_amdgcn_cvt_pk_f32_fp8((int)uu[t + 3], false);
            floatx2 q7 = __builtin_amdgcn_cvt_pk_f32_fp8((int)uu[t + 3], true);
            a0.x += q0.x; a0.y += q0.y; a0.z += q1.x; a0.w += q1.y;
            a1.x += q2.x; a1.y += q2.y; a1.z += q3.x; a1.w += q3.y;
            a2.x += q4.x; a2.y += q4.y; a2.z += q5.x; a2.w += q5.y;
            a3.x += q6.x; a3.y += q6.y; a3.z += q7.x; a3.w += q7.y;
        }
    }
    return make_float4(a0.x + a1.x + a2.x + a3.x,
                       a0.y + a1.y + a2.y + a3.y,
                       a0.z + a1.z + a2.z + a3.z,
                       a0.w + a1.w + a2.w + a3.w);
}

// ---------------- fused gather + MFMA GEMM (layer 1 -> hs2 fp8 directly) ----------------
// block = 256 threads = 16 nodes. gathered row relu'd into fp16 LDS tile, MFMA vs W2
// fragments (built from global, no W LDS), fp32 epilogue transpose via Os, fp8 out.

__global__ __launch_bounds__(256) void k_gather_gemm(const unsigned int* __restrict__ hs8,
                                                     const int* __restrict__ csr,
                                                     const int* __restrict__ off,
                                                     const float* __restrict__ dinv,
                                                     const float* __restrict__ bias,
                                                     const float* __restrict__ W,
                                                     unsigned int* __restrict__ hs_out,
                                                     int N) {
    __shared__ _Float16 Xs[16 * 72];
    __shared__ float Os[16 * 68];
    int tid = threadIdx.x;
    int r = tid >> 4, l = tid & 15;
    int lane = tid & 63, w = tid >> 6;
    int m = lane & 15, g = lane >> 4;
    int gw4 = (r & 3) << 4;
    int v = blockIdx.x * 16 + r;

    // B fragments first (global-load latency overlaps the gather)
    f16x8 B0, B1;
    {
        int n = (w << 4) + m;
        const float* wp = W + (g << 3) * 64 + n;
#pragma unroll
        for (int j = 0; j < 8; ++j) B0[j] = (_Float16)wp[j * 64];
        wp += 32 * 64;
#pragma unroll
        for (int j = 0; j < 8; ++j) B1[j] = (_Float16)wp[j * 64];
    }
    if (blockIdx.x == 0 && tid < 16)
        hs_out[(size_t)N * 16 + tid] = 0u;               // zero pad row for gather2

    float dv = 0.f;
    float4 h = make_float4(0.f, 0.f, 0.f, 0.f);
    if (v < N) {
        dv = dinv[v];
        float4 bv = ((const float4*)bias)[l];
        float4 acc = gather_rows(hs8, csr, off[v], off[v + 1], v, l, gw4, N);
        h.x = fmaxf(acc.x * dv + bv.x, 0.f);
        h.y = fmaxf(acc.y * dv + bv.y, 0.f);
        h.z = fmaxf(acc.z * dv + bv.z, 0.f);
        h.w = fmaxf(acc.w * dv + bv.w, 0.f);
    }
    {
        f16x4 hv;
        hv[0] = (_Float16)h.x; hv[1] = (_Float16)h.y;
        hv[2] = (_Float16)h.z; hv[3] = (_Float16)h.w;
        *(f16x4*)(Xs + r * 72 + (l << 2)) = hv;
    }
    __syncthreads();

    f16x8 A0 = *(const f16x8*)(Xs + m * 72 + (g << 3));
    f16x8 A1 = *(const f16x8*)(Xs + m * 72 + 32 + (g << 3));
    f32x4 acc2 = {0.f, 0.f, 0.f, 0.f};
    acc2 = __builtin_amdgcn_mfma_f32_16x16x32_f16(A0, B0, acc2, 0, 0, 0);
    acc2 = __builtin_amdgcn_mfma_f32_16x16x32_f16(A1, B1, acc2, 0, 0, 0);
#pragma unroll
    for (int j = 0; j < 4; ++j)
        Os[((g << 2) + j) * 68 + (w << 4) + m] = acc2[j];
    __syncthreads();

    if (v < N) {
        float4 o = *(const float4*)(Os + r * 68 + (l << 2));
        int p = 0;
        p = __builtin_amdgcn_cvt_pk_fp8_f32(o.x * dv, o.y * dv, p, false);
        p = __builtin_amdgcn_cvt_pk_fp8_f32(o.z * dv, o.w * dv, p, true);
        hs_out[(size_t)v * 16 + l] = (unsigned int)p;
    }
}

// ---------------- fused gather (layer 2) + mean-pool: atomics into out ----------------
// block = 16 nodes; batch sorted -> 1-2 graph segments per block. Each group computes
// relu(acc*dinv+b2)/count[g]; segment leaders reduce over LDS and atomicAdd into out.

__global__ __launch_bounds__(256) void k_gather_pool(const unsigned int* __restrict__ hs8,
                                                     const int* __restrict__ csr,
                                                     const int* __restrict__ off,
                                                     const float* __restrict__ dinv,
                                                     const float* __restrict__ bias,
                                                     const int* __restrict__ batch,
                                                     const int* __restrict__ goff,
                                                     float* __restrict__ out, int N) {
    __shared__ float vals[16][68];
    __shared__ int gid[16];
    int tid = threadIdx.x;
    int r = tid >> 4, l = tid & 15;
    int gw4 = (r & 3) << 4;
    int v = blockIdx.x * 16 + r;

    float4 val = make_float4(0.f, 0.f, 0.f, 0.f);
    int g = -1;
    if (v < N) {
        g = batch[v];
        float dv = dinv[v];
        float4 bv = ((const float4*)bias)[l];
        float4 acc = gather_rows(hs8, csr, off[v], off[v + 1], v, l, gw4, N);
        float inv = 1.0f / (float)(goff[g + 1] - goff[g]);
        val.x = fmaxf(acc.x * dv + bv.x, 0.f) * inv;
        val.y = fmaxf(acc.y * dv + bv.y, 0.f) * inv;
        val.z = fmaxf(acc.z * dv + bv.z, 0.f) * inv;
        val.w = fmaxf(acc.w * dv + bv.w, 0.f) * inv;
    }
    *(float4*)(&vals[r][l << 2]) = val;
    if (l == 0) gid[r] = g;
    __syncthreads();

    if (v < N) {
        bool leader = (r == 0) || (gid[r - 1] != g);
        if (leader) {
            float4 s = val;
            for (int rr = r + 1; rr < 16 && gid[rr] == g; ++rr) {
                float4 t = *(const float4*)(&vals[rr][l << 2]);
                s.x += t.x; s.y += t.y; s.z += t.z; s.w += t.w;
            }
            float* op = out + (size_t)g * DIM + (l << 2);
            atomicAdd(op + 0, s.x);
            atomicAdd(op + 1, s.y);
            atomicAdd(op + 2, s.z);
            atomicAdd(op + 3, s.w);
        }
    }
}

// ---------------- launch ----------------

static inline int cdiv(int a, int b) { return (a + b - 1) / b; }

extern "C" void kernel_launch(void* const* d_in, const int* in_sizes, int n_in,
                              void* d_out, int out_size, void* d_ws, size_t ws_size,
                              hipStream_t stream) {
    const float* x   = (const float*)d_in[0];
    const float* W1  = (const float*)d_in[1];
    const float* b1  = (const float*)d_in[2];
    const float* W2  = (const float*)d_in[3];
    const float* b2  = (const float*)d_in[4];
    const int*   ei  = (const int*)d_in[5];
    const int*   bat = (const int*)d_in[6];

    const int N = in_sizes[0] / DIM;
    const int E = in_sizes[5] / 2;
    const int G = out_size / DIM;
    const int NB = cdiv(N, BINSZ);           // <= MAXBINS
    const int M  = NB * PB;                  // scan length
    const int* src = ei;
    const int* dst = ei + E;
    float* out = (float*)d_out;

    // workspace: hs1 | hs2 | spare | dinv | off | goff | C | S | bsums | csr
    // bkt aliases hs1 (dead before gemm1).
    __half* hs1    = (__half*)d_ws;                         // (N+1)*64 h region
    __half* hs2    = hs1 + (size_t)(N + 1) * DIM;           // (N+1)*64 h region
    __half* spare  = hs2 + (size_t)(N + 1) * DIM;           // N*64 h (unused)
    float*  dinv   = (float*)(spare + (size_t)N * DIM);     // N f
    int*    off    = (int*)(dinv + N);                      // N+1 i
    int*    goff   = off + (N + 1);                         // G+1 i
    int*    C      = goff + (G + 1);                        // PB*NB i
    int*    S      = C + (size_t)PB * NB;                   // PB*NB i
    int*    bsums  = S + (size_t)PB * NB;                   // up to 1024 i
    int*    csr    = bsums + 1024;                          // E i
    int*    bkt    = (int*)hs1;                             // E i (aliased)

    k_hist<<<PB, 256, 0, stream>>>(dst, C, E, NB);
    int nb2 = cdiv(M, 4096);
    k_scanA<<<nb2, 1024, 0, stream>>>(C, S, bsums, NB, M);
    k_scanB<<<1, 1024, 0, stream>>>(bsums, nb2);
    k_bucket<<<PB, 256, 0, stream>>>(src, dst, S, bsums, bkt, E, NB);
    k_binsort<<<NB, 256, 0, stream>>>(bkt, S, bsums, csr, off, dinv, bat, goff,
                                      out, N, G, E, NB);

    // layer 1 transform: hs1 = (x @ W1) * dinv (fp8 e4m3), MFMA
    k_gemm<<<cdiv(N + 1, 16), 256, 0, stream>>>(x, W1, dinv, (unsigned int*)hs1, N);

    // fused: agg1 = gather(hs1)+b1 ; hs2 = (relu(agg1) @ W2) * dinv (fp8), MFMA
    k_gather_gemm<<<cdiv(N, 16), 256, 0, stream>>>((const unsigned int*)hs1, csr, off,
                                                   dinv, b1, W2, (unsigned int*)hs2, N);

    // fused: layer 2 gather + bias + relu + mean-pool (atomics into out)
    k_gather_pool<<<cdiv(N, 16), 256, 0, stream>>>((const unsigned int*)hs2, csr, off,
                                                   dinv, b2, bat, goff, out, N);
}